// Round 1
// baseline (889.200 us; speedup 1.0000x reference)
//
#include <hip/hip_runtime.h>
#include <math.h>

#define B_   16
#define S_   4096
#define D_   768
#define H_   384
#define NTOK (B_ * S_)
#define MT   32      // tokens per block
#define DKC  16      // k-chunk
#define KTOP 40

// ---------------------------------------------------------------------------
// Kernel 1: fused scores = sigmoid(W2 . gelu(LN(x@W1 + b1)) + b2)
// Block: 256 threads = 4 waves. Each wave owns 8 token-rows; each lane owns
// 6 columns: j = lane*2 + (c>>1)*128 + (c&1), c in [0,6). 64 lanes * 6 = 384.
// ---------------------------------------------------------------------------
__global__ __launch_bounds__(256) void score_kernel(
    const float* __restrict__ features,
    const float* __restrict__ W1,
    const float* __restrict__ b1,
    const float* __restrict__ gamma,
    const float* __restrict__ beta,
    const float* __restrict__ W2,
    const float* __restrict__ b2,
    float* __restrict__ scores)
{
    __shared__ float As[MT][DKC + 2];   // +2 pad: break bank aliasing on write
    __shared__ float Bs[DKC][H_];

    const int tid  = threadIdx.x;
    const int lane = tid & 63;
    const int wave = tid >> 6;
    const int tokenBase = blockIdx.x * MT;

    float acc[8][6];
#pragma unroll
    for (int r = 0; r < 8; ++r)
#pragma unroll
        for (int c = 0; c < 6; ++c) acc[r][c] = 0.0f;

    for (int d0 = 0; d0 < D_; d0 += DKC) {
        // --- stage A tile [MT][DKC]: 512 floats, 2 per thread (float2) ---
        {
            const int t  = tid >> 3;          // 0..31
            const int dd = (tid & 7) * 2;     // 0,2,..,14
            const float2 v = *(const float2*)(features + (size_t)(tokenBase + t) * D_ + d0 + dd);
            As[t][dd]     = v.x;
            As[t][dd + 1] = v.y;
        }
        // --- stage B tile [DKC][384]: 6144 floats, 24 per thread ---
#pragma unroll
        for (int k = 0; k < 24; ++k) {
            const int i  = tid + k * 256;
            const int dd = i / H_;
            const int j  = i - dd * H_;
            Bs[dd][j] = W1[(size_t)(d0 + dd) * H_ + j];
        }
        __syncthreads();

#pragma unroll
        for (int dd = 0; dd < DKC; ++dd) {
            float a[8];
#pragma unroll
            for (int r = 0; r < 8; ++r) a[r] = As[wave * 8 + r][dd];
            float b[6];
#pragma unroll
            for (int c = 0; c < 3; ++c) {
                const float2 bv = *(const float2*)&Bs[dd][lane * 2 + c * 128];
                b[2 * c]     = bv.x;
                b[2 * c + 1] = bv.y;
            }
#pragma unroll
            for (int r = 0; r < 8; ++r)
#pragma unroll
                for (int c = 0; c < 6; ++c)
                    acc[r][c] = fmaf(a[r], b[c], acc[r][c]);
        }
        __syncthreads();
    }

    // --- epilogue: per-column constants ---
    float b1_[6], g_[6], be_[6], w2_[6];
#pragma unroll
    for (int c = 0; c < 6; ++c) {
        const int j = lane * 2 + (c >> 1) * 128 + (c & 1);
        b1_[c] = b1[j];
        g_[c]  = gamma[j];
        be_[c] = beta[j];
        w2_[c] = W2[j];
    }
    const float bb2 = b2[0];

#pragma unroll
    for (int r = 0; r < 8; ++r) {
        float h[6];
        float sum = 0.0f;
#pragma unroll
        for (int c = 0; c < 6; ++c) { h[c] = acc[r][c] + b1_[c]; sum += h[c]; }
#pragma unroll
        for (int off = 32; off >= 1; off >>= 1) sum += __shfl_xor(sum, off, 64);
        const float mu = sum * (1.0f / H_);

        float vs = 0.0f;
#pragma unroll
        for (int c = 0; c < 6; ++c) { const float d = h[c] - mu; vs += d * d; }
#pragma unroll
        for (int off = 32; off >= 1; off >>= 1) vs += __shfl_xor(vs, off, 64);
        const float rs = rsqrtf(vs * (1.0f / H_) + 1e-5f);

        float sdot = 0.0f;
#pragma unroll
        for (int c = 0; c < 6; ++c) {
            const float y  = (h[c] - mu) * rs * g_[c] + be_[c];
            const float ge = 0.5f * y * (1.0f + erff(y * 0.70710678118654752f));
            sdot = fmaf(ge, w2_[c], sdot);
        }
#pragma unroll
        for (int off = 32; off >= 1; off >>= 1) sdot += __shfl_xor(sdot, off, 64);

        const float s  = sdot + bb2;
        const float sc = 1.0f / (1.0f + expf(-s));
        if (lane == 0) scores[tokenBase + wave * 8 + r] = sc;
    }
}

// ---------------------------------------------------------------------------
// Kernel 2: per-batch exact top-40 (ties -> lower index, matching lax.top_k),
// gather safety tokens, write indices as float32.
// One block per batch (16 blocks x 256 threads).
// ---------------------------------------------------------------------------
__global__ __launch_bounds__(256) void topk_kernel(
    const float* __restrict__ scores,
    const float* __restrict__ features,
    float* __restrict__ out_tokens,   // [B, KTOP, D]
    float* __restrict__ out_idx)      // [B, KTOP] (float values)
{
    __shared__ float sc[S_];          // 16 KB
    __shared__ int   sel[KTOP];
    __shared__ float bestv[4];
    __shared__ int   besti[4];

    const int b   = blockIdx.x;
    const int tid = threadIdx.x;

    for (int i = tid; i < S_; i += 256) sc[i] = scores[b * S_ + i];
    __syncthreads();

    for (int it = 0; it < KTOP; ++it) {
        float bv = -1.0f;   // all live scores in (0,1); killed entries = -2
        int   bi = -1;
        for (int i = tid; i < S_; i += 256) {
            const float v = sc[i];
            if (v > bv) { bv = v; bi = i; }   // ascending i: first max kept
        }
#pragma unroll
        for (int off = 32; off >= 1; off >>= 1) {
            const float ov = __shfl_xor(bv, off, 64);
            const int   oi = __shfl_xor(bi, off, 64);
            if (ov > bv || (ov == bv && oi < bi && oi >= 0)) { bv = ov; bi = oi; }
        }
        const int w = tid >> 6;
        if ((tid & 63) == 0) { bestv[w] = bv; besti[w] = bi; }
        __syncthreads();
        if (tid == 0) {
            float fv = bestv[0]; int fi = besti[0];
            for (int q = 1; q < 4; ++q) {
                if (bestv[q] > fv || (bestv[q] == fv && besti[q] < fi)) {
                    fv = bestv[q]; fi = besti[q];
                }
            }
            sel[it]  = fi;
            sc[fi]   = -2.0f;
        }
        __syncthreads();
    }

    // gather selected feature rows (coalesced)
    for (int it = 0; it < KTOP; ++it) {
        const int idx = sel[it];
        const float* src = features + ((size_t)b * S_ + idx) * D_;
        float* dst = out_tokens + ((size_t)b * KTOP + it) * D_;
        for (int i = tid; i < D_; i += 256) dst[i] = src[i];
    }
    if (tid < KTOP) out_idx[b * KTOP + tid] = (float)sel[tid];
}

// ---------------------------------------------------------------------------
extern "C" void kernel_launch(void* const* d_in, const int* in_sizes, int n_in,
                              void* d_out, int out_size, void* d_ws, size_t ws_size,
                              hipStream_t stream)
{
    const float* features = (const float*)d_in[0];
    const float* W1       = (const float*)d_in[1];
    const float* b1       = (const float*)d_in[2];
    const float* gamma    = (const float*)d_in[3];
    const float* beta     = (const float*)d_in[4];
    const float* W2       = (const float*)d_in[5];
    const float* b2       = (const float*)d_in[6];

    float* scores = (float*)d_ws;                    // 65536 floats = 256 KB
    float* out    = (float*)d_out;
    float* out_tokens = out;                         // [16,40,768]
    float* out_idx    = out + (size_t)B_ * KTOP * D_; // [16,40]

    score_kernel<<<NTOK / MT, 256, 0, stream>>>(
        features, W1, b1, gamma, beta, W2, b2, scores);
    topk_kernel<<<B_, 256, 0, stream>>>(scores, features, out_tokens, out_idx);
}

// Round 2
// 510.371 us; speedup vs baseline: 1.7423x; 1.7423x over previous
//
#include <hip/hip_runtime.h>
#include <math.h>

#define B_   16
#define S_   4096
#define D_   768
#define H_   384
#define NTOK (B_ * S_)
#define KTOP 40
#define NTILES 24          // 384/16 n-tiles
#define KCH    24          // 768/32 k-chunks

typedef __attribute__((ext_vector_type(8))) short bf16x8;
typedef __attribute__((ext_vector_type(4))) float f32x4;

static __device__ __forceinline__ unsigned short f2bf(float x) {
    union { float f; unsigned u; } v; v.f = x;
    unsigned r = v.u + 0x7FFF + ((v.u >> 16) & 1);   // RNE
    return (unsigned short)(r >> 16);
}
static __device__ __forceinline__ float bf2f(unsigned short h) {
    union { unsigned u; float f; } v; v.u = ((unsigned)h) << 16; return v.f;
}

// ---------------------------------------------------------------------------
// Kernel 0: pack W1 (fp32 [768][384]) into MFMA B-fragment layout, bf16 hi/lo.
// Fragment element j of lane: B[k = chunk*32 + (lane>>4)*8 + j][n = ntile*16 + (lane&15)]
// packed[( (ntile*KCH + chunk)*64 + lane )*8 + j]
// ---------------------------------------------------------------------------
__global__ __launch_bounds__(64) void pack_w1(const float* __restrict__ W1,
                                              unsigned short* __restrict__ bh,
                                              unsigned short* __restrict__ bl)
{
    const int nt   = blockIdx.x;        // 0..23
    const int ch   = blockIdx.y;        // 0..23
    const int lane = threadIdx.x;
    const int n    = nt * 16 + (lane & 15);
    const int k0   = ch * 32 + (lane >> 4) * 8;

    unsigned short h8[8], l8[8];
#pragma unroll
    for (int j = 0; j < 8; ++j) {
        const float v = W1[(size_t)(k0 + j) * H_ + n];
        const unsigned short h = f2bf(v);
        h8[j] = h;
        l8[j] = f2bf(v - bf2f(h));
    }
    const size_t base = ((size_t)(nt * KCH + ch) * 64 + lane) * 8;
#pragma unroll
    for (int j = 0; j < 8; ++j) { bh[base + j] = h8[j]; bl[base + j] = l8[j]; }
}

// ---------------------------------------------------------------------------
// Kernel 1: fused scores. Block = 64 tokens x 384 cols. 4 waves; wave w owns
// n-tiles w*6..w*6+5 and all 64 rows (4 m-subtiles of 16).
// 3-term bf16-split MFMA GEMM, fp32-accurate. Epilogue: LN + GELU + W2 + sigmoid.
// ---------------------------------------------------------------------------
__global__ __launch_bounds__(256) void score_kernel(
    const float* __restrict__ features,
    const unsigned short* __restrict__ bh_g,
    const unsigned short* __restrict__ bl_g,
    const float* __restrict__ b1,
    const float* __restrict__ gamma,
    const float* __restrict__ beta,
    const float* __restrict__ W2,
    const float* __restrict__ b2,
    float* __restrict__ scores)
{
    __shared__ unsigned short Ah[64][40];   // pad 32->40: 2-way bank alias only
    __shared__ unsigned short Al[64][40];
    __shared__ float red[4][64];
    __shared__ float mu_s[64];
    __shared__ float rs_s[64];

    const int tid  = threadIdx.x;
    const int lane = tid & 63;
    const int w    = tid >> 6;
    const int base = blockIdx.x * 64;
    const int cl   = lane & 15;
    const int p    = lane >> 4;

    f32x4 acc[4][6];
#pragma unroll
    for (int m = 0; m < 4; ++m)
#pragma unroll
        for (int t = 0; t < 6; ++t) acc[m][t] = (f32x4){0.f, 0.f, 0.f, 0.f};

    // staging map: element f in [0,512): row = f>>3, col4 = (f&7)*4
    const int f0 = tid, f1 = tid + 256;
    const int r0 = f0 >> 3, c0 = (f0 & 7) * 4;
    const int r1 = f1 >> 3, c1 = (f1 & 7) * 4;

    float4 p0 = *(const float4*)(features + (size_t)(base + r0) * D_ + c0);
    float4 p1 = *(const float4*)(features + (size_t)(base + r1) * D_ + c1);

    for (int c = 0; c < KCH; ++c) {
        if (c) __syncthreads();
        // convert + write staged chunk
        {
            unsigned short h0 = f2bf(p0.x), h1 = f2bf(p0.y), h2 = f2bf(p0.z), h3 = f2bf(p0.w);
            Ah[r0][c0] = h0; Ah[r0][c0+1] = h1; Ah[r0][c0+2] = h2; Ah[r0][c0+3] = h3;
            Al[r0][c0]   = f2bf(p0.x - bf2f(h0));
            Al[r0][c0+1] = f2bf(p0.y - bf2f(h1));
            Al[r0][c0+2] = f2bf(p0.z - bf2f(h2));
            Al[r0][c0+3] = f2bf(p0.w - bf2f(h3));
            unsigned short g0 = f2bf(p1.x), g1 = f2bf(p1.y), g2 = f2bf(p1.z), g3 = f2bf(p1.w);
            Ah[r1][c1] = g0; Ah[r1][c1+1] = g1; Ah[r1][c1+2] = g2; Ah[r1][c1+3] = g3;
            Al[r1][c1]   = f2bf(p1.x - bf2f(g0));
            Al[r1][c1+1] = f2bf(p1.y - bf2f(g1));
            Al[r1][c1+2] = f2bf(p1.z - bf2f(g2));
            Al[r1][c1+3] = f2bf(p1.w - bf2f(g3));
        }
        // prefetch next chunk (overlaps barrier + MFMA below)
        if (c + 1 < KCH) {
            const int d0 = (c + 1) * 32;
            p0 = *(const float4*)(features + (size_t)(base + r0) * D_ + d0 + c0);
            p1 = *(const float4*)(features + (size_t)(base + r1) * D_ + d0 + c1);
        }
        __syncthreads();

        // B fragments for this wave's 6 n-tiles (from packed L2-resident W1)
        bf16x8 bhf[6], blf[6];
#pragma unroll
        for (int t = 0; t < 6; ++t) {
            const size_t bb = ((size_t)((w * 6 + t) * KCH + c) * 64 + lane) * 8;
            bhf[t] = *(const bf16x8*)(bh_g + bb);
            blf[t] = *(const bf16x8*)(bl_g + bb);
        }
        // A fragments for the 4 m-subtiles
        bf16x8 ahf[4], alf[4];
#pragma unroll
        for (int m = 0; m < 4; ++m) {
            const int row = m * 16 + cl;
            const int k0  = p * 8;
            ahf[m] = *(const bf16x8*)&Ah[row][k0];
            alf[m] = *(const bf16x8*)&Al[row][k0];
        }
#pragma unroll
        for (int m = 0; m < 4; ++m)
#pragma unroll
            for (int t = 0; t < 6; ++t) {
                acc[m][t] = __builtin_amdgcn_mfma_f32_16x16x32_bf16(ahf[m], bhf[t], acc[m][t], 0, 0, 0);
                acc[m][t] = __builtin_amdgcn_mfma_f32_16x16x32_bf16(ahf[m], blf[t], acc[m][t], 0, 0, 0);
                acc[m][t] = __builtin_amdgcn_mfma_f32_16x16x32_bf16(alf[m], bhf[t], acc[m][t], 0, 0, 0);
            }
    }

    // ---- epilogue: per-column constants ----
    float b1v[6], gv[6], bev[6], w2v[6];
#pragma unroll
    for (int t = 0; t < 6; ++t) {
        const int n = (w * 6 + t) * 16 + cl;
        b1v[t] = b1[n]; gv[t] = gamma[n]; bev[t] = beta[n]; w2v[t] = W2[n];
    }
    // h = acc + b1
#pragma unroll
    for (int m = 0; m < 4; ++m)
#pragma unroll
        for (int t = 0; t < 6; ++t)
#pragma unroll
            for (int r = 0; r < 4; ++r) acc[m][t][r] += b1v[t];

    // pass 1: row sums -> mean
#pragma unroll
    for (int m = 0; m < 4; ++m) {
        float sm[4] = {0.f, 0.f, 0.f, 0.f};
#pragma unroll
        for (int t = 0; t < 6; ++t)
#pragma unroll
            for (int r = 0; r < 4; ++r) sm[r] += acc[m][t][r];
#pragma unroll
        for (int r = 0; r < 4; ++r) {
#pragma unroll
            for (int off = 1; off <= 8; off <<= 1) sm[r] += __shfl_xor(sm[r], off, 64);
        }
        if (cl == 0) {
#pragma unroll
            for (int r = 0; r < 4; ++r) red[w][m * 16 + p * 4 + r] = sm[r];
        }
    }
    __syncthreads();
    if (tid < 64) mu_s[tid] = (red[0][tid] + red[1][tid] + red[2][tid] + red[3][tid]) * (1.0f / H_);
    __syncthreads();

    // pass 2: variance (two-pass, matches reference)
#pragma unroll
    for (int m = 0; m < 4; ++m) {
        float mur[4];
#pragma unroll
        for (int r = 0; r < 4; ++r) mur[r] = mu_s[m * 16 + p * 4 + r];
        float sm[4] = {0.f, 0.f, 0.f, 0.f};
#pragma unroll
        for (int t = 0; t < 6; ++t)
#pragma unroll
            for (int r = 0; r < 4; ++r) { const float d = acc[m][t][r] - mur[r]; sm[r] += d * d; }
#pragma unroll
        for (int r = 0; r < 4; ++r) {
#pragma unroll
            for (int off = 1; off <= 8; off <<= 1) sm[r] += __shfl_xor(sm[r], off, 64);
        }
        if (cl == 0) {
#pragma unroll
            for (int r = 0; r < 4; ++r) red[w][m * 16 + p * 4 + r] = sm[r];
        }
    }
    __syncthreads();
    if (tid < 64) rs_s[tid] = rsqrtf((red[0][tid] + red[1][tid] + red[2][tid] + red[3][tid]) * (1.0f / H_) + 1e-5f);
    __syncthreads();

    // pass 3: y = LN*gamma+beta, gelu, dot with W2
#pragma unroll
    for (int m = 0; m < 4; ++m) {
        float mur[4], rsr[4];
#pragma unroll
        for (int r = 0; r < 4; ++r) { mur[r] = mu_s[m * 16 + p * 4 + r]; rsr[r] = rs_s[m * 16 + p * 4 + r]; }
        float sm[4] = {0.f, 0.f, 0.f, 0.f};
#pragma unroll
        for (int t = 0; t < 6; ++t)
#pragma unroll
            for (int r = 0; r < 4; ++r) {
                const float y  = (acc[m][t][r] - mur[r]) * rsr[r] * gv[t] + bev[t];
                const float ge = 0.5f * y * (1.0f + erff(y * 0.70710678118654752f));
                sm[r] = fmaf(ge, w2v[t], sm[r]);
            }
#pragma unroll
        for (int r = 0; r < 4; ++r) {
#pragma unroll
            for (int off = 1; off <= 8; off <<= 1) sm[r] += __shfl_xor(sm[r], off, 64);
        }
        if (cl == 0) {
#pragma unroll
            for (int r = 0; r < 4; ++r) red[w][m * 16 + p * 4 + r] = sm[r];
        }
    }
    __syncthreads();
    if (tid < 64) {
        const float s = red[0][tid] + red[1][tid] + red[2][tid] + red[3][tid] + b2[0];
        scores[base + tid] = 1.0f / (1.0f + expf(-s));
    }
}

// ---------------------------------------------------------------------------
// Kernel 2: per-batch exact top-40 via byte-wise radix select on float bits
// (scores > 0 so uint order == float order). Ties -> lower index.
// ---------------------------------------------------------------------------
__global__ __launch_bounds__(256) void select_kernel(const float* __restrict__ scores,
                                                     int* __restrict__ sel)
{
    __shared__ unsigned int bits_s[S_];     // 16 KB
    __shared__ unsigned int hist[256];
    __shared__ int s_byte, s_above, s_rem;
    __shared__ unsigned int s_ngt, s_neq;
    __shared__ unsigned int candV[64];
    __shared__ int candI[64];
    __shared__ int eqI[256];

    const int b   = blockIdx.x;
    const int tid = threadIdx.x;

    for (int i = tid; i < S_; i += 256)
        bits_s[i] = __float_as_uint(scores[b * S_ + i]);
    if (tid == 0) { s_rem = KTOP; s_ngt = 0u; s_neq = 0u; }

    unsigned int prefix = 0u, mask = 0u;
    for (int pb = 3; pb >= 0; --pb) {
        hist[tid] = 0u;
        __syncthreads();
        for (int i = tid; i < S_; i += 256) {
            const unsigned int u = bits_s[i];
            if ((u & mask) == prefix) atomicAdd(&hist[(u >> (8 * pb)) & 255u], 1u);
        }
        __syncthreads();
        if (tid == 0) {
            int c = 0, v = 255;
            for (; v >= 0; --v) { c += (int)hist[v]; if (c >= s_rem) break; }
            s_byte  = v;
            s_above = c - (int)hist[v];
            s_rem   = s_rem - s_above;
        }
        __syncthreads();
        prefix |= ((unsigned int)s_byte) << (8 * pb);
        mask   |= 0xFFu << (8 * pb);
        __syncthreads();
    }
    const unsigned int T = prefix;
    const int need = s_rem;                 // 1..: #ties at T to keep

    for (int i = tid; i < S_; i += 256) {
        const unsigned int u = bits_s[i];
        if (u > T) {
            const unsigned int pos = atomicAdd(&s_ngt, 1u);
            candV[pos] = u; candI[pos] = i;          // n_gt <= 39 guaranteed
        } else if (u == T) {
            const unsigned int pos = atomicAdd(&s_neq, 1u);
            if (pos < 256u) eqI[pos] = i;
        }
    }
    __syncthreads();
    const int ngt = (int)s_ngt;
    const int neq = (int)(s_neq < 256u ? s_neq : 256u);
    // keep the `need` smallest indices among ties
    for (int j = tid; j < neq; j += 256) {
        int rank = 0;
        for (int l = 0; l < neq; ++l) rank += (eqI[l] < eqI[j]) ? 1 : 0;
        if (rank < need) { candV[ngt + rank] = T; candI[ngt + rank] = eqI[j]; }
    }
    __syncthreads();
    // final ordering: (score desc, index asc)
    if (tid < KTOP) {
        const unsigned int u = candV[tid];
        const int idx = candI[tid];
        int rank = 0;
        for (int j = 0; j < KTOP; ++j)
            rank += (candV[j] > u || (candV[j] == u && candI[j] < idx)) ? 1 : 0;
        sel[b * KTOP + rank] = idx;
    }
}

// ---------------------------------------------------------------------------
// Kernel 3: gather selected rows + write indices (as float). Grid (40,16).
// ---------------------------------------------------------------------------
__global__ __launch_bounds__(192) void gather_kernel(const float* __restrict__ features,
                                                     const int* __restrict__ sel,
                                                     float* __restrict__ out_tok,
                                                     float* __restrict__ out_idx)
{
    const int i = blockIdx.x;   // 0..39
    const int b = blockIdx.y;   // 0..15
    const int idx = sel[b * KTOP + i];
    const float4* src = (const float4*)(features + ((size_t)b * S_ + idx) * D_);
    float4* dst = (float4*)(out_tok + ((size_t)b * KTOP + i) * D_);
    dst[threadIdx.x] = src[threadIdx.x];
    if (threadIdx.x == 0) out_idx[b * KTOP + i] = (float)idx;
}

// ---------------------------------------------------------------------------
extern "C" void kernel_launch(void* const* d_in, const int* in_sizes, int n_in,
                              void* d_out, int out_size, void* d_ws, size_t ws_size,
                              hipStream_t stream)
{
    const float* features = (const float*)d_in[0];
    const float* W1       = (const float*)d_in[1];
    const float* b1       = (const float*)d_in[2];
    const float* gamma    = (const float*)d_in[3];
    const float* beta     = (const float*)d_in[4];
    const float* W2       = (const float*)d_in[5];
    const float* b2       = (const float*)d_in[6];

    // ws layout
    unsigned short* bh = (unsigned short*)d_ws;            // 294912 elems (576 KB)
    unsigned short* bl = bh + (size_t)D_ * H_;             // 576 KB
    float* scores      = (float*)(bl + (size_t)D_ * H_);   // 256 KB
    int*   sel         = (int*)(scores + NTOK);            // 2.5 KB

    float* out        = (float*)d_out;
    float* out_tokens = out;                               // [16,40,768]
    float* out_idx    = out + (size_t)B_ * KTOP * D_;      // [16,40]

    pack_w1<<<dim3(NTILES, KCH), 64, 0, stream>>>(W1, bh, bl);
    score_kernel<<<NTOK / 64, 256, 0, stream>>>(features, bh, bl, b1, gamma, beta, W2, b2, scores);
    select_kernel<<<B_, 256, 0, stream>>>(scores, sel);
    gather_kernel<<<dim3(KTOP, B_), 192, 0, stream>>>(features, sel, out_tokens, out_idx);
}